// Round 3
// baseline (264.715 us; speedup 1.0000x reference)
//
#include <hip/hip_runtime.h>

// out = RMSNorm(sum_tp(input) + residual) * w ; also emit residual_out.
//   input [TP=8, T=8192, H=4096] fp32 ; residual [T,H] ; norm_weight [H]
// Outputs concatenated in d_out: out [T,H], residual_out [T,H].
// Memory-bound: 1.476 GB compulsory traffic. v2 = NT loads/stores (5.92 TB/s).
// v3: wave-per-row — no __syncthreads, no LDS, reduce = 6 shfl_xor.
constexpr int TP = 8;
constexpr int NT = 8192;
constexpr int H  = 4096;
constexpr float EPS = 1e-6f;

typedef float f32x4 __attribute__((ext_vector_type(4)));

// 256 threads = 4 waves per block; each wave owns one token row.
// Lane l handles float4 columns l, l+64, ..., l+15*64 (coalesced).
__global__ __launch_bounds__(256) void fused_ar_addres_rmsnorm(
    const f32x4* __restrict__ in4,     // [TP*T*H/4]
    const f32x4* __restrict__ res4,    // [T*H/4]
    const f32x4* __restrict__ w4,      // [H/4]
    f32x4* __restrict__ out4,          // [T*H/4]
    f32x4* __restrict__ ro4)           // [T*H/4]
{
    const int tid  = threadIdx.x;
    const int lane = tid & 63;
    const int wave = tid >> 6;
    const int row  = blockIdx.x * 4 + wave;
    const size_t row4 = (size_t)row * (H / 4);
    constexpr size_t RANK_STRIDE4 = (size_t)NT * (H / 4);

    constexpr int CH = (H / 4) / 64;   // 16 float4 chunks per lane
    f32x4 acc[CH];
    float ssq = 0.0f;

    #pragma unroll
    for (int i = 0; i < CH; ++i) {
        const int c = i * 64 + lane;               // float4 column
        f32x4 s = __builtin_nontemporal_load(&res4[row4 + c]);
        #pragma unroll
        for (int r = 0; r < TP; ++r) {
            f32x4 v = __builtin_nontemporal_load(&in4[(size_t)r * RANK_STRIDE4 + row4 + c]);
            s += v;
        }
        acc[i] = s;
        __builtin_nontemporal_store(s, &ro4[row4 + c]);   // residual_out
        ssq = fmaf(s.x, s.x, ssq);
        ssq = fmaf(s.y, s.y, ssq);
        ssq = fmaf(s.z, s.z, ssq);
        ssq = fmaf(s.w, s.w, ssq);
    }

    // Wave-wide butterfly reduce: all 64 lanes end with the row total.
    #pragma unroll
    for (int off = 32; off > 0; off >>= 1)
        ssq += __shfl_xor(ssq, off, 64);

    const float inv = rsqrtf(ssq * (1.0f / (float)H) + EPS);

    #pragma unroll
    for (int i = 0; i < CH; ++i) {
        const int c = i * 64 + lane;
        const f32x4 g = w4[c];                     // 16 KiB, cached (reused)
        const f32x4 s = acc[i];
        f32x4 o = s * inv * g;
        __builtin_nontemporal_store(o, &out4[row4 + c]);
    }
}

extern "C" void kernel_launch(void* const* d_in, const int* in_sizes, int n_in,
                              void* d_out, int out_size, void* d_ws, size_t ws_size,
                              hipStream_t stream) {
    const f32x4* in  = (const f32x4*)d_in[0];
    const f32x4* res = (const f32x4*)d_in[1];
    const f32x4* w   = (const f32x4*)d_in[2];
    f32x4* out = (f32x4*)d_out;
    f32x4* res_out = out + (size_t)NT * (H / 4);   // outputs concatenated: out, residual_out

    fused_ar_addres_rmsnorm<<<dim3(NT / 4), dim3(256), 0, stream>>>(in, res, w, out, res_out);
}

// Round 4
// 251.165 us; speedup vs baseline: 1.0539x; 1.0539x over previous
//
#include <hip/hip_runtime.h>

// out = RMSNorm(sum_tp(input) + residual) * w ; also emit residual_out.
//   input [TP=8, T=8192, H=4096] fp32 ; residual [T,H] ; norm_weight [H]
// Outputs concatenated in d_out: out [T,H], residual_out [T,H].
// Memory-bound: 1.476 GB compulsory traffic; floor at 6.29 TB/s ≈ 235 µs.
// v2 (block-per-row + NT loads/stores) = 249.5 µs = 5.92 TB/s.
// v3 (wave-per-row) REGRESSED to 264.7 — acc[16] register pressure beat the
// barrier saving. v4 = v2 + preload weight before the barrier.
constexpr int TP = 8;
constexpr int NT = 8192;
constexpr int H  = 4096;
constexpr float EPS = 1e-6f;

typedef float f32x4 __attribute__((ext_vector_type(4)));

// One block per token row. 256 threads x 4 float4 chunks each.
__global__ __launch_bounds__(256) void fused_ar_addres_rmsnorm(
    const f32x4* __restrict__ in4,     // [TP*T*H/4]
    const f32x4* __restrict__ res4,    // [T*H/4]
    const f32x4* __restrict__ w4,      // [H/4]
    f32x4* __restrict__ out4,          // [T*H/4]
    f32x4* __restrict__ ro4)           // [T*H/4]
{
    const int row = blockIdx.x;
    const int tid = threadIdx.x;
    const size_t row4 = (size_t)row * (H / 4);
    constexpr size_t RANK_STRIDE4 = (size_t)NT * (H / 4);

    constexpr int CH = (H / 4) / 256;  // 4 chunks/thread
    f32x4 acc[CH];
    f32x4 wreg[CH];
    float ssq = 0.0f;

    #pragma unroll
    for (int i = 0; i < CH; ++i) {
        const int c = i * 256 + tid;               // float4 column
        f32x4 s = __builtin_nontemporal_load(&res4[row4 + c]);
        #pragma unroll
        for (int r = 0; r < TP; ++r) {
            f32x4 v = __builtin_nontemporal_load(&in4[(size_t)r * RANK_STRIDE4 + row4 + c]);
            s += v;
        }
        acc[i] = s;
        __builtin_nontemporal_store(s, &ro4[row4 + c]);   // residual_out
        ssq = fmaf(s.x, s.x, ssq);
        ssq = fmaf(s.y, s.y, ssq);
        ssq = fmaf(s.z, s.z, ssq);
        ssq = fmaf(s.w, s.w, ssq);
    }

    // Preload gamma before the barrier: L2-hot but ~200cy — hide it here so
    // the post-barrier epilogue is pure VALU + store.
    #pragma unroll
    for (int i = 0; i < CH; ++i)
        wreg[i] = w4[i * 256 + tid];

    // Block reduction: 64-lane wave shuffle, then LDS across the 4 waves.
    #pragma unroll
    for (int off = 32; off > 0; off >>= 1)
        ssq += __shfl_down(ssq, off, 64);

    __shared__ float sdata[4];
    const int lane = tid & 63;
    const int wave = tid >> 6;
    if (lane == 0) sdata[wave] = ssq;
    __syncthreads();
    const float total = sdata[0] + sdata[1] + sdata[2] + sdata[3];
    const float inv = rsqrtf(total * (1.0f / (float)H) + EPS);

    #pragma unroll
    for (int i = 0; i < CH; ++i) {
        const int c = i * 256 + tid;
        const f32x4 s = acc[i];
        f32x4 o = s * inv * wreg[i];
        __builtin_nontemporal_store(o, &out4[row4 + c]);
    }
}

extern "C" void kernel_launch(void* const* d_in, const int* in_sizes, int n_in,
                              void* d_out, int out_size, void* d_ws, size_t ws_size,
                              hipStream_t stream) {
    const f32x4* in  = (const f32x4*)d_in[0];
    const f32x4* res = (const f32x4*)d_in[1];
    const f32x4* w   = (const f32x4*)d_in[2];
    f32x4* out = (f32x4*)d_out;
    f32x4* res_out = out + (size_t)NT * (H / 4);   // outputs concatenated: out, residual_out

    fused_ar_addres_rmsnorm<<<dim3(NT), dim3(256), 0, stream>>>(in, res, w, out, res_out);
}